// Round 1
// baseline (513.863 us; speedup 1.0000x reference)
//
#include <hip/hip_runtime.h>

// Self-attention B=32,C=256,N=1024 on gfx950.
// S[i,j] = q_i . k_j + rel_i . q_j  (K=512 concat), softmax over j, O = P V^T.
// All MFMA inputs fp16, accumulate fp32. Workspace ~65 MB.

#define NB 32
#define NC 256
#define NNN 1024

typedef _Float16 f16;
typedef __attribute__((ext_vector_type(8))) _Float16 half8;
typedef __attribute__((ext_vector_type(4))) float f32x4;

__device__ __forceinline__ f32x4 mfma16(half8 a, half8 b, f32x4 c) {
  return __builtin_amdgcn_mfma_f32_16x16x32_f16(a, b, c, 0, 0, 0);
}

__device__ __forceinline__ float sel4(float a0, float a1, float a2, float a3, int r) {
  return r == 0 ? a0 : (r == 1 ? a1 : (r == 2 ? a2 : a3));
}

// ---------------- prep: x -> xT fp16 [B][N][C]; W -> fp16; RT[n][c] ----------------
__global__ __launch_bounds__(256) void k_prep(
    const float* __restrict__ x, const float* __restrict__ Wq,
    const float* __restrict__ Wk, const float* __restrict__ Wv,
    const float* __restrict__ relh, const float* __restrict__ relw,
    f16* __restrict__ xT, f16* __restrict__ Wh, f16* __restrict__ RT) {
  int bid = blockIdx.x, tid = threadIdx.x;
  if (bid < 128) {
    // transpose+cast: 32 b's x 4 n-chunks of 256
    int b = bid >> 2;
    int n = ((bid & 3) << 8) + tid;
    const float* xp = x + (size_t)b * NC * NNN + n;   // x[b][c][n]
    f16* dst = xT + ((size_t)b * NNN + n) * NC;       // xT[b][n][c]
    #pragma unroll 4
    for (int c0 = 0; c0 < NC; c0 += 8) {
      half8 h;
      #pragma unroll
      for (int u = 0; u < 8; ++u) h[u] = (f16)xp[(size_t)(c0 + u) * NNN];
      *(half8*)(dst + c0) = h;
    }
  } else if (bid < 896) {
    // cast Wq,Wk,Wv to fp16, packed [3][C][C]
    int i = ((bid - 128) << 8) + tid;  // 0..196607
    int w = i >> 16, j = i & 65535;
    const float* src = (w == 0) ? Wq : ((w == 1) ? Wk : Wv);
    Wh[i] = (f16)src[j];
  } else {
    // RT[n][c] = rel_w[c][n>>5] + rel_h[c][n&31]
    int n = bid - 896;
    int c = tid;
    RT[n * NC + c] = (f16)(relw[c * 32 + (n >> 5)] + relh[c * 32 + (n & 31)]);
  }
}

// ---------------- proj: QT[b][n][o], KT[b][n][o], V[b][o][n]  (fp16) ----------------
__global__ __launch_bounds__(256, 2) void k_proj(
    const f16* __restrict__ xT, const f16* __restrict__ Wh,
    const float* __restrict__ bq, const float* __restrict__ bk,
    const float* __restrict__ bv,
    f16* __restrict__ QT, f16* __restrict__ KT, f16* __restrict__ V) {
  int b = blockIdx.x >> 4;
  int n0 = (blockIdx.x & 15) << 6;
  int tid = threadIdx.x;
  int wave = tid >> 6, lane = tid & 63;
  int lq = lane & 15, g = lane >> 4;
  int ow = wave << 6;  // this wave's o-strip
  const f16* xTb = xT + ((size_t)b * NNN + n0) * NC;

  // ---- QT (which=0) and KT (which=1): D[n][o] = sum_c xT[n][c] * W[o][c] + b[o]
  for (int which = 0; which < 2; ++which) {
    const f16* Wp = Wh + which * 65536;
    const float* bias = which ? bk : bq;
    f16* outp = which ? KT : QT;
    f32x4 acc[4][4];
    #pragma unroll
    for (int f = 0; f < 4; ++f) {
      float bf = bias[ow + 16 * f + lq];
      #pragma unroll
      for (int m = 0; m < 4; ++m) acc[m][f] = (f32x4){bf, bf, bf, bf};
    }
    #pragma unroll
    for (int kk = 0; kk < 8; ++kk) {
      int cb = kk * 32 + 8 * g;
      half8 xa[4], wb[4];
      #pragma unroll
      for (int m = 0; m < 4; ++m)
        xa[m] = *(const half8*)(xTb + (size_t)(16 * m + lq) * NC + cb);
      #pragma unroll
      for (int f = 0; f < 4; ++f)
        wb[f] = *(const half8*)(Wp + (size_t)(ow + 16 * f + lq) * NC + cb);
      #pragma unroll
      for (int m = 0; m < 4; ++m)
        #pragma unroll
        for (int f = 0; f < 4; ++f)
          acc[m][f] = mfma16(xa[m], wb[f], acc[m][f]);
    }
    #pragma unroll
    for (int m = 0; m < 4; ++m)
      #pragma unroll
      for (int f = 0; f < 4; ++f)
        #pragma unroll
        for (int r = 0; r < 4; ++r)
          outp[((size_t)b * NNN + n0 + 16 * m + 4 * g + r) * NC + ow + 16 * f + lq] =
              (f16)acc[m][f][r];
  }

  // ---- V: D[o][n] = sum_c Wv[o][c] * x[c][n] + bv[o]
  {
    const f16* Wp = Wh + 2 * 65536;
    f32x4 acc[4][4];  // [o-frag][n-frag]
    #pragma unroll
    for (int m = 0; m < 4; ++m)
      #pragma unroll
      for (int r = 0; r < 4; ++r) {
        float bf = bv[ow + 16 * m + 4 * g + r];
        #pragma unroll
        for (int f = 0; f < 4; ++f) acc[m][f][r] = bf;
      }
    #pragma unroll
    for (int kk = 0; kk < 8; ++kk) {
      int cb = kk * 32 + 8 * g;
      half8 va[4], xb[4];
      #pragma unroll
      for (int m = 0; m < 4; ++m)
        va[m] = *(const half8*)(Wp + (size_t)(ow + 16 * m + lq) * NC + cb);
      #pragma unroll
      for (int f = 0; f < 4; ++f)
        xb[f] = *(const half8*)(xTb + (size_t)(16 * f + lq) * NC + cb);
      #pragma unroll
      for (int m = 0; m < 4; ++m)
        #pragma unroll
        for (int f = 0; f < 4; ++f)
          acc[m][f] = mfma16(va[m], xb[f], acc[m][f]);
    }
    #pragma unroll
    for (int m = 0; m < 4; ++m)
      #pragma unroll
      for (int f = 0; f < 4; ++f)
        #pragma unroll
        for (int r = 0; r < 4; ++r)
          V[((size_t)b * NC + ow + 16 * m + 4 * g + r) * NNN + n0 + 16 * f + lq] =
              (f16)acc[m][f][r];
  }
}

// ---------------- flash: per block 64 q-rows (4 waves x 16), BN=64 ----------------
__global__ __launch_bounds__(256, 2) void k_flash(
    const f16* __restrict__ QT, const f16* __restrict__ KT,
    const f16* __restrict__ V, const f16* __restrict__ RT,
    float* __restrict__ out) {
  int bid = blockIdx.x;
  int swz = (bid & 7) * 64 + (bid >> 3);  // XCD-chunked: one batch's 16 blocks share an XCD
  int b = swz >> 4;
  int i0 = (swz & 15) << 6;
  int tid = threadIdx.x;
  int wave = tid >> 6, lane = tid & 63;
  int lq = lane & 15, g = lane >> 4;
  int iw = i0 + 16 * wave;

  __shared__ f16 Plds[4][16][72];  // wave-private P tiles, stride 72 (16B-aligned rows)

  const f16* QTb = QT + (size_t)b * NNN * NC;
  const f16* KTb = KT + (size_t)b * NNN * NC;
  const f16* Vb  = V  + (size_t)b * NC * NNN;

  // A-fragments: Q part (kk<8) + rel part (kk>=8), held in registers for whole kernel
  half8 QA[16];
  #pragma unroll
  for (int kk = 0; kk < 8; ++kk)
    QA[kk] = *(const half8*)(QTb + (size_t)(iw + lq) * NC + kk * 32 + 8 * g);
  #pragma unroll
  for (int kk = 0; kk < 8; ++kk)
    QA[8 + kk] = *(const half8*)(RT + (size_t)(iw + lq) * NC + kk * 32 + 8 * g);

  f32x4 acc[16];  // O^T: rows c (16 frags), cols i (= lq)
  #pragma unroll
  for (int cf = 0; cf < 16; ++cf) acc[cf] = (f32x4){0.f, 0.f, 0.f, 0.f};
  float m[4]    = {-1e30f, -1e30f, -1e30f, -1e30f};
  float lsum[4] = {0.f, 0.f, 0.f, 0.f};

  #pragma unroll 1
  for (int jt = 0; jt < 16; ++jt) {
    int j0 = jt * 64;
    // ---- S = QK^T + R Q : D-layout rows i = 4g+r, cols j = 16f+lq
    f32x4 S[4];
    #pragma unroll
    for (int f = 0; f < 4; ++f) S[f] = (f32x4){0.f, 0.f, 0.f, 0.f};
    #pragma unroll
    for (int kk = 0; kk < 16; ++kk) {
      const f16* Bp = (kk < 8) ? KTb : QTb;
      int cb = (kk & 7) * 32 + 8 * g;
      #pragma unroll
      for (int f = 0; f < 4; ++f) {
        half8 bb = *(const half8*)(Bp + (size_t)(j0 + 16 * f + lq) * NC + cb);
        S[f] = mfma16(QA[kk], bb, S[f]);
      }
    }
    // ---- online softmax (row i = 4g + r lives in 16-lane group g, reg r)
    float sc[4];
    #pragma unroll
    for (int r = 0; r < 4; ++r) {
      float t = fmaxf(fmaxf(S[0][r], S[1][r]), fmaxf(S[2][r], S[3][r]));
      t = fmaxf(t, __shfl_xor(t, 1));
      t = fmaxf(t, __shfl_xor(t, 2));
      t = fmaxf(t, __shfl_xor(t, 4));
      t = fmaxf(t, __shfl_xor(t, 8));
      float mn = fmaxf(m[r], t);
      sc[r] = __expf(m[r] - mn);
      m[r] = mn;
      float s = 0.f;
      #pragma unroll
      for (int f = 0; f < 4; ++f) {
        float p = __expf(S[f][r] - mn);
        S[f][r] = p;
        s += p;
      }
      s += __shfl_xor(s, 1);
      s += __shfl_xor(s, 2);
      s += __shfl_xor(s, 4);
      s += __shfl_xor(s, 8);
      lsum[r] = lsum[r] * sc[r] + s;
    }
    // ---- redistribute scale to "per-lane row = lq" form (acc cols are i = lq)
    {
      int srcl = (lq >> 2) << 4;  // any lane of group lq>>2 holds sc[] for rows 4*(lq>>2)+r
      float s0 = __shfl(sc[0], srcl);
      float s1 = __shfl(sc[1], srcl);
      float s2 = __shfl(sc[2], srcl);
      float s3 = __shfl(sc[3], srcl);
      float sci = sel4(s0, s1, s2, s3, lq & 3);
      #pragma unroll
      for (int cf = 0; cf < 16; ++cf) {
        acc[cf][0] *= sci; acc[cf][1] *= sci; acc[cf][2] *= sci; acc[cf][3] *= sci;
      }
    }
    // ---- P -> LDS (wave-private), read back as B-operand (P^T) fragments
    #pragma unroll
    for (int f = 0; f < 4; ++f)
      #pragma unroll
      for (int r = 0; r < 4; ++r)
        Plds[wave][4 * g + r][16 * f + lq] = (f16)S[f][r];
    asm volatile("s_waitcnt lgkmcnt(0)" ::: "memory");
    half8 PA0 = *(const half8*)(&Plds[wave][lq][8 * g]);
    half8 PA1 = *(const half8*)(&Plds[wave][lq][32 + 8 * g]);
    // ---- O^T += V * P^T
    #pragma unroll
    for (int cf = 0; cf < 16; ++cf) {
      half8 v0 = *(const half8*)(Vb + (size_t)(16 * cf + lq) * NNN + j0 + 8 * g);
      half8 v1 = *(const half8*)(Vb + (size_t)(16 * cf + lq) * NNN + j0 + 32 + 8 * g);
      acc[cf] = mfma16(v0, PA0, acc[cf]);
      acc[cf] = mfma16(v1, PA1, acc[cf]);
    }
  }

  // ---- epilogue: normalize, store out[b][c][i] (fp32), i-contiguous
  float li;
  {
    float linv[4];
    #pragma unroll
    for (int r = 0; r < 4; ++r) linv[r] = 1.f / lsum[r];
    int srcl = (lq >> 2) << 4;
    float l0 = __shfl(linv[0], srcl);
    float l1 = __shfl(linv[1], srcl);
    float l2 = __shfl(linv[2], srcl);
    float l3 = __shfl(linv[3], srcl);
    li = sel4(l0, l1, l2, l3, lq & 3);
  }
  #pragma unroll
  for (int cf = 0; cf < 16; ++cf)
    #pragma unroll
    for (int r = 0; r < 4; ++r)
      out[((size_t)b * NC + 16 * cf + 4 * g + r) * NNN + iw + lq] = acc[cf][r] * li;
}

// ---------------- launch ----------------
extern "C" void kernel_launch(void* const* d_in, const int* in_sizes, int n_in,
                              void* d_out, int out_size, void* d_ws, size_t ws_size,
                              hipStream_t stream) {
  const float* x    = (const float*)d_in[0];
  const float* Wq   = (const float*)d_in[1];
  const float* bq   = (const float*)d_in[2];
  const float* Wk   = (const float*)d_in[3];
  const float* bk   = (const float*)d_in[4];
  const float* Wv   = (const float*)d_in[5];
  const float* bv   = (const float*)d_in[6];
  const float* relh = (const float*)d_in[7];
  const float* relw = (const float*)d_in[8];

  char* ws = (char*)d_ws;
  const size_t SZ_MAT = (size_t)NB * NNN * NC * sizeof(f16);  // 16 MB
  f16* xT = (f16*)(ws);
  f16* QT = (f16*)(ws + SZ_MAT);
  f16* KT = (f16*)(ws + 2 * SZ_MAT);
  f16* V  = (f16*)(ws + 3 * SZ_MAT);
  f16* RT = (f16*)(ws + 4 * SZ_MAT);                         // 512 KB
  f16* Wh = (f16*)(ws + 4 * SZ_MAT + (size_t)NNN * NC * sizeof(f16));  // 384 KB

  k_prep<<<dim3(1920), dim3(256), 0, stream>>>(x, Wq, Wk, Wv, relh, relw, xT, Wh, RT);
  k_proj<<<dim3(512), dim3(256), 0, stream>>>(xT, Wh, bq, bk, bv, QT, KT, V);
  k_flash<<<dim3(512), dim3(256), 0, stream>>>(QT, KT, V, RT, (float*)d_out);
}

// Round 2
// 445.840 us; speedup vs baseline: 1.1526x; 1.1526x over previous
//
#include <hip/hip_runtime.h>

// Self-attention B=32,C=256,N=1024 on gfx950.
// S[i,j] = q_i.k_j + rel_i.q_j (K=512 concat), online softmax, O = P V^T.
// R1: split-j flash (2 halves -> 1024 blocks, 4 blocks/CU), LDS-staged KQ tile
// via swizzled global_load_lds; LDS-staged x strip in proj. fp16 MFMA, fp32 acc.

#define NB 32
#define NC 256
#define NNN 1024

typedef _Float16 f16;
typedef __attribute__((ext_vector_type(8))) _Float16 half8;
typedef __attribute__((ext_vector_type(4))) float f32x4;

__device__ __forceinline__ f32x4 mfma16(half8 a, half8 b, f32x4 c) {
  return __builtin_amdgcn_mfma_f32_16x16x32_f16(a, b, c, 0, 0, 0);
}
__device__ __forceinline__ float sel4(float a0, float a1, float a2, float a3, int r) {
  return r == 0 ? a0 : (r == 1 ? a1 : (r == 2 ? a2 : a3));
}
// async global->LDS, 16B/lane; LDS dest = uniform base + lane*16 (linear),
// swizzle achieved by pre-swizzling the per-lane GLOBAL source (guide rule 21).
__device__ __forceinline__ void gload16(const f16* g, f16* l) {
  __builtin_amdgcn_global_load_lds(
      (const __attribute__((address_space(1))) void*)g,
      (__attribute__((address_space(3))) void*)l, 16, 0, 0);
}

// ---------------- prep: x -> xT fp16 [B][N][C]; W -> fp16; RT[n][c] ----------------
__global__ __launch_bounds__(256) void k_prep(
    const float* __restrict__ x, const float* __restrict__ Wq,
    const float* __restrict__ Wk, const float* __restrict__ Wv,
    const float* __restrict__ relh, const float* __restrict__ relw,
    f16* __restrict__ xT, f16* __restrict__ Wh, f16* __restrict__ RT) {
  int bid = blockIdx.x, tid = threadIdx.x;
  if (bid < 128) {
    int b = bid >> 2;
    int n = ((bid & 3) << 8) + tid;
    const float* xp = x + (size_t)b * NC * NNN + n;   // x[b][c][n], coalesced in n
    f16* dst = xT + ((size_t)b * NNN + n) * NC;       // xT[b][n][c]
    #pragma unroll 4
    for (int c0 = 0; c0 < NC; c0 += 8) {
      half8 h;
      #pragma unroll
      for (int u = 0; u < 8; ++u) h[u] = (f16)xp[(size_t)(c0 + u) * NNN];
      *(half8*)(dst + c0) = h;
    }
  } else if (bid < 896) {
    int i = ((bid - 128) << 8) + tid;
    int w = i >> 16, j = i & 65535;
    const float* src = (w == 0) ? Wq : ((w == 1) ? Wk : Wv);
    Wh[i] = (f16)src[j];
  } else {
    int n = bid - 896;
    int c = tid;
    RT[n * NC + c] = (f16)(relw[c * 32 + (n >> 5)] + relh[c * 32 + (n & 31)]);
  }
}

// -------- proj: KQ[b][n][0:256]=K^T row, [256:512]=Q^T row; V[b][o][n] (fp16) --------
__global__ __launch_bounds__(256, 4) void k_proj(
    const f16* __restrict__ xT, const f16* __restrict__ Wh,
    const float* __restrict__ bq, const float* __restrict__ bk,
    const float* __restrict__ bv,
    f16* __restrict__ KQ, f16* __restrict__ V) {
  int b = blockIdx.x >> 4;
  int n0 = (blockIdx.x & 15) << 6;
  int tid = threadIdx.x;
  int wave = tid >> 6, lane = tid & 63;
  int lq = lane & 15, g = lane >> 4;
  int ow = wave << 6;
  const f16* xTb = xT + ((size_t)b * NNN + n0) * NC;

  __shared__ f16 XS[64][256];  // x strip, 32KB, 16B-slot XOR swizzle per row

  {
    int li = lane & 31;
    #pragma unroll
    for (int q2 = 0; q2 < 8; ++q2) {
      int r2 = wave * 16 + q2 * 2;         // instr covers rows r2, r2+1 (512B each)
      int r = r2 + (lane >> 5);
      int slot = (li & 0x10) | ((li ^ (r & 15)) & 0xF);
      gload16(xTb + (size_t)r * NC + slot * 8, &XS[r2][0]);
    }
  }
  asm volatile("s_waitcnt vmcnt(0)" ::: "memory");
  __syncthreads();

  // Q (which=0 -> KQ[..][256+o]) and K (which=1 -> KQ[..][o])
  #pragma unroll 1
  for (int which = 0; which < 2; ++which) {
    const f16* Wp = Wh + which * 65536;
    const float* bias = which ? bk : bq;
    int koff = which ? 0 : 256;
    f32x4 acc[4][4];
    #pragma unroll
    for (int f = 0; f < 4; ++f) {
      float bf = bias[ow + 16 * f + lq];
      #pragma unroll
      for (int m = 0; m < 4; ++m) acc[m][f] = (f32x4){bf, bf, bf, bf};
    }
    #pragma unroll
    for (int kk = 0; kk < 8; ++kk) {
      int cb = kk * 32 + 8 * g;
      int s = 4 * kk + g;
      int p = (s & 0x10) | ((s ^ lq) & 0xF);
      half8 xa[4], wb[4];
      #pragma unroll
      for (int m = 0; m < 4; ++m)
        xa[m] = *(const half8*)(&XS[16 * m + lq][p * 8]);
      #pragma unroll
      for (int f = 0; f < 4; ++f)
        wb[f] = *(const half8*)(Wp + (size_t)(ow + 16 * f + lq) * NC + cb);
      #pragma unroll
      for (int m = 0; m < 4; ++m)
        #pragma unroll
        for (int f = 0; f < 4; ++f)
          acc[m][f] = mfma16(xa[m], wb[f], acc[m][f]);
    }
    #pragma unroll
    for (int m = 0; m < 4; ++m)
      #pragma unroll
      for (int f = 0; f < 4; ++f)
        #pragma unroll
        for (int r = 0; r < 4; ++r)
          KQ[((size_t)b * NNN + n0 + 16 * m + 4 * g + r) * 512 + koff + ow + 16 * f + lq] =
              (f16)acc[m][f][r];
  }

  // V: D[o][n] = sum_c Wv[o][c] x[n][c] + bv[o]
  {
    const f16* Wp = Wh + 2 * 65536;
    f32x4 acc[4][4];
    #pragma unroll
    for (int m = 0; m < 4; ++m)
      #pragma unroll
      for (int r = 0; r < 4; ++r) {
        float bf = bv[ow + 16 * m + 4 * g + r];
        #pragma unroll
        for (int f = 0; f < 4; ++f) acc[m][f][r] = bf;
      }
    #pragma unroll
    for (int kk = 0; kk < 8; ++kk) {
      int cb = kk * 32 + 8 * g;
      int s = 4 * kk + g;
      int p = (s & 0x10) | ((s ^ lq) & 0xF);
      half8 va[4], xb[4];
      #pragma unroll
      for (int m = 0; m < 4; ++m)
        va[m] = *(const half8*)(Wp + (size_t)(ow + 16 * m + lq) * NC + cb);
      #pragma unroll
      for (int f = 0; f < 4; ++f)
        xb[f] = *(const half8*)(&XS[16 * f + lq][p * 8]);
      #pragma unroll
      for (int m = 0; m < 4; ++m)
        #pragma unroll
        for (int f = 0; f < 4; ++f)
          acc[m][f] = mfma16(va[m], xb[f], acc[m][f]);
    }
    #pragma unroll
    for (int m = 0; m < 4; ++m)
      #pragma unroll
      for (int f = 0; f < 4; ++f)
        #pragma unroll
        for (int r = 0; r < 4; ++r)
          V[((size_t)b * NC + ow + 16 * m + 4 * g + r) * NNN + n0 + 16 * f + lq] =
              (f16)acc[m][f][r];
  }
}

// -------- flash2: split-j (2 halves). 1024 blocks, 4 waves, 16 q-rows/wave, jt=32 --------
__global__ __launch_bounds__(256, 4) void k_flash2(
    const f16* __restrict__ KQ, const f16* __restrict__ V,
    const f16* __restrict__ RT,
    f16* __restrict__ O1, f16* __restrict__ O2,
    float* __restrict__ Msc, float* __restrict__ Lsc) {
  int bid = blockIdx.x;
  int xcd = bid & 7, idx = bid >> 3;      // XCD-local batches: xcd gets b in [4x,4x+4)
  int b = xcd * 4 + (idx >> 5);
  int sub = idx & 31;
  int half = sub >> 4, strip = sub & 15;
  int i0 = strip << 6;
  int jbase = half << 9;
  int tid = threadIdx.x;
  int wave = tid >> 6, lane = tid & 63;
  int lq = lane & 15, g = lane >> 4;
  int iw = i0 + 16 * wave;

  __shared__ f16 KQS[32][512];   // 32KB j-tile (K||Q rows), swizzled 16B slots
  __shared__ f16 Plds[4][16][32]; // wave-private P

  const f16* KQb = KQ + ((size_t)b * NNN << 9);
  const f16* Vb = V + (size_t)b * NC * NNN;

  f32x4 acc[16];
  #pragma unroll
  for (int cf = 0; cf < 16; ++cf) acc[cf] = (f32x4){0.f, 0.f, 0.f, 0.f};
  float m[4] = {-1e30f, -1e30f, -1e30f, -1e30f};
  float lsum[4] = {0.f, 0.f, 0.f, 0.f};

  #pragma unroll 1
  for (int jt = 0; jt < 16; ++jt) {
    int j0 = jbase + jt * 32;
    // ---- stage KQ rows j0..j0+31 (1KB each = one gload_lds), swizzled source
    #pragma unroll
    for (int rr = 0; rr < 8; ++rr) {
      int r = wave * 8 + rr;
      int slot = (lane & 0x30) | ((lane ^ (r & 15)) & 0xF);
      gload16(KQb + ((size_t)(j0 + r) << 9) + slot * 8, &KQS[r][0]);
    }
    asm volatile("s_waitcnt vmcnt(0)" ::: "memory");
    __syncthreads();

    // ---- S = [Q_i|R_i] . [K_j|Q_j]  (K=512): rows i=4g+r, cols j=16f+lq
    f32x4 S[2];
    S[0] = (f32x4){0.f, 0.f, 0.f, 0.f};
    S[1] = (f32x4){0.f, 0.f, 0.f, 0.f};
    #pragma unroll
    for (int kk = 0; kk < 16; ++kk) {
      half8 a = (kk < 8)
          ? *(const half8*)(KQb + ((size_t)(iw + lq) << 9) + 256 + kk * 32 + 8 * g)
          : *(const half8*)(RT + (size_t)(iw + lq) * NC + (kk - 8) * 32 + 8 * g);
      int s = 4 * kk + g;
      int p = (s & 0x30) | ((s ^ lq) & 0xF);
      S[0] = mfma16(a, *(const half8*)(&KQS[lq][p * 8]), S[0]);
      S[1] = mfma16(a, *(const half8*)(&KQS[16 + lq][p * 8]), S[1]);
    }

    // ---- online softmax (row i=4g+r across 16 lanes of group g)
    float sc[4];
    #pragma unroll
    for (int r = 0; r < 4; ++r) {
      float t = fmaxf(S[0][r], S[1][r]);
      t = fmaxf(t, __shfl_xor(t, 1));
      t = fmaxf(t, __shfl_xor(t, 2));
      t = fmaxf(t, __shfl_xor(t, 4));
      t = fmaxf(t, __shfl_xor(t, 8));
      float mn = fmaxf(m[r], t);
      sc[r] = __expf(m[r] - mn);
      m[r] = mn;
      float ssum = 0.f;
      #pragma unroll
      for (int f = 0; f < 2; ++f) {
        float p = __expf(S[f][r] - mn);
        S[f][r] = p;
        ssum += p;
      }
      ssum += __shfl_xor(ssum, 1);
      ssum += __shfl_xor(ssum, 2);
      ssum += __shfl_xor(ssum, 4);
      ssum += __shfl_xor(ssum, 8);
      lsum[r] = lsum[r] * sc[r] + ssum;
    }
    // ---- P -> LDS, read back as B-operand
    #pragma unroll
    for (int f = 0; f < 2; ++f)
      #pragma unroll
      for (int r = 0; r < 4; ++r)
        Plds[wave][4 * g + r][16 * f + lq] = (f16)S[f][r];
    asm volatile("s_waitcnt lgkmcnt(0)" ::: "memory");
    __builtin_amdgcn_sched_barrier(0);
    half8 pa = *(const half8*)(&Plds[wave][lq][8 * g]);
    // ---- rescale acc (cols are i = lq)
    {
      int srcl = (lq >> 2) << 4;
      float s0 = __shfl(sc[0], srcl);
      float s1 = __shfl(sc[1], srcl);
      float s2 = __shfl(sc[2], srcl);
      float s3 = __shfl(sc[3], srcl);
      float sci = sel4(s0, s1, s2, s3, lq & 3);
      #pragma unroll
      for (int cf = 0; cf < 16; ++cf) {
        acc[cf][0] *= sci; acc[cf][1] *= sci; acc[cf][2] *= sci; acc[cf][3] *= sci;
      }
    }
    // ---- O^T += V . P^T  (K=32, one MFMA per 16-c frag)
    #pragma unroll
    for (int cf = 0; cf < 16; ++cf) {
      half8 vv = *(const half8*)(Vb + ((size_t)(16 * cf + lq) << 10) + j0 + 8 * g);
      acc[cf] = mfma16(vv, pa, acc[cf]);
    }
    __syncthreads();  // protect KQS before next stage
  }

  // ---- epilogue: partial (unnormalized) O^T f16 + m,l f32
  f16* Oc = half ? O2 : O1;
  #pragma unroll
  for (int cf = 0; cf < 16; ++cf)
    #pragma unroll
    for (int r = 0; r < 4; ++r)
      Oc[((size_t)(b * NC + 16 * cf + 4 * g + r) << 10) + iw + lq] = (f16)acc[cf][r];
  int mlb = half * (NB * NNN) + b * NNN + iw;
  if (lq == 0) {
    #pragma unroll
    for (int r = 0; r < 4; ++r) {
      Msc[mlb + 4 * g + r] = m[r];
      Lsc[mlb + 4 * g + r] = lsum[r];
    }
  }
}

// ---------------- combine two halves ----------------
__global__ __launch_bounds__(256) void k_combine(
    const f16* __restrict__ O1, const f16* __restrict__ O2,
    const float* __restrict__ Msc, const float* __restrict__ Lsc,
    float* __restrict__ out) {
  int t = blockIdx.x * 256 + threadIdx.x;  // [0, 1M)
  int i8 = t & 127;
  int ci = (t >> 7) & 255;
  int b = t >> 15;
  size_t base = ((size_t)(b * NC + ci) << 10) + i8 * 8;
  half8 o1 = *(const half8*)(O1 + base);
  half8 o2 = *(const half8*)(O2 + base);
  int mb = b * NNN + i8 * 8;
  float res[8];
  #pragma unroll
  for (int u = 0; u < 8; ++u) {
    float m1 = Msc[mb + u], m2 = Msc[NB * NNN + mb + u];
    float l1 = Lsc[mb + u], l2 = Lsc[NB * NNN + mb + u];
    float M = fmaxf(m1, m2);
    float w1 = __expf(m1 - M), w2 = __expf(m2 - M);
    float inv = 1.f / (w1 * l1 + w2 * l2);
    res[u] = (w1 * (float)o1[u] + w2 * (float)o2[u]) * inv;
  }
  #pragma unroll
  for (int u = 0; u < 8; ++u) out[base + u] = res[u];
}

// ---------------- launch ----------------
extern "C" void kernel_launch(void* const* d_in, const int* in_sizes, int n_in,
                              void* d_out, int out_size, void* d_ws, size_t ws_size,
                              hipStream_t stream) {
  const float* x = (const float*)d_in[0];
  const float* Wq = (const float*)d_in[1];
  const float* bq = (const float*)d_in[2];
  const float* Wk = (const float*)d_in[3];
  const float* bk = (const float*)d_in[4];
  const float* Wv = (const float*)d_in[5];
  const float* bv = (const float*)d_in[6];
  const float* relh = (const float*)d_in[7];
  const float* relw = (const float*)d_in[8];

  char* ws = (char*)d_ws;
  const size_t MB = 1 << 20;
  f16* xT = (f16*)(ws);                    // 16MB (reused as O1 after proj)
  f16* KQ = (f16*)(ws + 16 * MB);          // 32MB
  f16* V = (f16*)(ws + 48 * MB);           // 16MB
  f16* RT = (f16*)(ws + 64 * MB);          // 512KB
  f16* Wh = (f16*)(ws + 64 * MB + 512 * 1024);  // 384KB
  f16* O2 = (f16*)(ws + 65 * MB);          // 16MB
  float* Msc = (float*)(ws + 81 * MB);     // 256KB
  float* Lsc = (float*)(ws + 81 * MB + 256 * 1024);  // 256KB
  f16* O1 = xT;

  k_prep<<<dim3(1920), dim3(256), 0, stream>>>(x, Wq, Wk, Wv, relh, relw, xT, Wh, RT);
  k_proj<<<dim3(512), dim3(256), 0, stream>>>(xT, Wh, bq, bk, bv, KQ, V);
  k_flash2<<<dim3(1024), dim3(256), 0, stream>>>(KQ, V, RT, O1, O2, Msc, Lsc);
  k_combine<<<dim3(4096), dim3(256), 0, stream>>>(O1, O2, Msc, Lsc, (float*)d_out);
}

// Round 3
// 326.360 us; speedup vs baseline: 1.5745x; 1.3661x over previous
//
#include <hip/hip_runtime.h>

// Self-attention B=32,C=256,N=1024 on gfx950.
// S[i,j] = q_i.k_j + rel_i.q_j (K=512 concat), online softmax, O = P V^T.
// R2: full-j flash (512 blocks = 2/CU), double-buffered KQ tile w/ prefetch
// (counted-wait pipeline), hoisted A-fragments, defer-max, lazy lsum reduce.
// x-transpose fused into proj. fp16 MFMA, fp32 accum.

#define NB 32
#define NC 256
#define NNN 1024

typedef _Float16 f16;
typedef __attribute__((ext_vector_type(8))) _Float16 half8;
typedef __attribute__((ext_vector_type(4))) float f32x4;
typedef __attribute__((ext_vector_type(4))) float float4v;

__device__ __forceinline__ f32x4 mfma16(half8 a, half8 b, f32x4 c) {
  return __builtin_amdgcn_mfma_f32_16x16x32_f16(a, b, c, 0, 0, 0);
}
__device__ __forceinline__ float sel4(float a0, float a1, float a2, float a3, int r) {
  return r == 0 ? a0 : (r == 1 ? a1 : (r == 2 ? a2 : a3));
}
// async global->LDS, 16B/lane; LDS dest = uniform base + lane*16 (linear).
__device__ __forceinline__ void gload16(const f16* g, f16* l) {
  __builtin_amdgcn_global_load_lds(
      (const __attribute__((address_space(1))) void*)g,
      (__attribute__((address_space(3))) void*)l, 16, 0, 0);
}

// ---------------- prep: W -> fp16 [3][C][C]; RT[n][c] = relw+relh ----------------
__global__ __launch_bounds__(256) void k_prep(
    const float* __restrict__ Wq, const float* __restrict__ Wk,
    const float* __restrict__ Wv, const float* __restrict__ relh,
    const float* __restrict__ relw, f16* __restrict__ Wh, f16* __restrict__ RT) {
  int bid = blockIdx.x, tid = threadIdx.x;
  if (bid < 192) {
    int base = (bid * 256 + tid) * 4;  // [0, 196608)
    int w = base >> 16, j = base & 65535;
    const float* src = (w == 0) ? Wq : ((w == 1) ? Wk : Wv);
    float4v v = *(const float4v*)(src + j);
    f16 h[4] = {(f16)v.x, (f16)v.y, (f16)v.z, (f16)v.w};
    *(half8*)0;  // (unused type anchor)
    Wh[base + 0] = h[0]; Wh[base + 1] = h[1]; Wh[base + 2] = h[2]; Wh[base + 3] = h[3];
  } else {
    int n = bid - 192;  // 0..1023
    int c = tid;
    RT[n * NC + c] = (f16)(relw[c * 32 + (n >> 5)] + relh[c * 32 + (n & 31)]);
  }
}

// -------- proj: stages x fp32 -> transposed f16 LDS tile (swizzled), then
//          KQ[b][n][0:256]=K row, [256:512]=Q row; V[b][o][n]  (fp16) --------
__global__ __launch_bounds__(256, 4) void k_proj(
    const float* __restrict__ x, const f16* __restrict__ Wh,
    const float* __restrict__ bq, const float* __restrict__ bk,
    const float* __restrict__ bv,
    f16* __restrict__ KQ, f16* __restrict__ V) {
  int b = blockIdx.x >> 4;
  int n0 = (blockIdx.x & 15) << 6;
  int tid = threadIdx.x;
  int wave = tid >> 6, lane = tid & 63;
  int lq = lane & 15, g = lane >> 4;
  int ow = wave << 6;

  __shared__ f16 XS[64][256];  // x^T strip [n][c], 32KB, 16B-slot XOR swizzle per row

  // ---- stage + transpose: x[b][c][n0+nn..+15] fp32 -> XS[n][c] f16 (swizzled)
  {
    const float* xb = x + (size_t)b * NC * NNN + n0;
    int cq = tid >> 2;          // 0..63 (c within 64-chunk)
    int nn = (tid & 3) << 4;    // 0,16,32,48
    #pragma unroll
    for (int cc = 0; cc < 4; ++cc) {
      int c = cc * 64 + cq;
      const float* src = xb + (size_t)c * NNN + nn;
      float vals[16];
      *(float4v*)(vals + 0)  = *(const float4v*)(src + 0);
      *(float4v*)(vals + 4)  = *(const float4v*)(src + 4);
      *(float4v*)(vals + 8)  = *(const float4v*)(src + 8);
      *(float4v*)(vals + 12) = *(const float4v*)(src + 12);
      int s = c >> 3;
      #pragma unroll
      for (int u = 0; u < 16; ++u) {
        int n = nn + u;
        int p = (s & 0x10) | ((s ^ (n & 15)) & 0xF);
        XS[n][p * 8 + (c & 7)] = (f16)vals[u];
      }
    }
  }
  __syncthreads();

  // ---- Q (which=0 -> KQ[..][256+o]) and K (which=1 -> KQ[..][o])
  #pragma unroll 1
  for (int which = 0; which < 2; ++which) {
    const f16* Wp = Wh + which * 65536;
    const float* bias = which ? bk : bq;
    int koff = which ? 0 : 256;
    f32x4 acc[4][4];
    #pragma unroll
    for (int f = 0; f < 4; ++f) {
      float bf = bias[ow + 16 * f + lq];
      #pragma unroll
      for (int m = 0; m < 4; ++m) acc[m][f] = (f32x4){bf, bf, bf, bf};
    }
    #pragma unroll
    for (int kk = 0; kk < 8; ++kk) {
      int cb = kk * 32 + 8 * g;
      int s = 4 * kk + g;
      int p = (s & 0x10) | ((s ^ lq) & 0xF);
      half8 xa[4], wb[4];
      #pragma unroll
      for (int m = 0; m < 4; ++m)
        xa[m] = *(const half8*)(&XS[16 * m + lq][p * 8]);
      #pragma unroll
      for (int f = 0; f < 4; ++f)
        wb[f] = *(const half8*)(Wp + (size_t)(ow + 16 * f + lq) * NC + cb);
      #pragma unroll
      for (int m = 0; m < 4; ++m)
        #pragma unroll
        for (int f = 0; f < 4; ++f)
          acc[m][f] = mfma16(xa[m], wb[f], acc[m][f]);
    }
    #pragma unroll
    for (int m = 0; m < 4; ++m)
      #pragma unroll
      for (int f = 0; f < 4; ++f)
        #pragma unroll
        for (int r = 0; r < 4; ++r)
          KQ[((size_t)b * NNN + n0 + 16 * m + 4 * g + r) * 512 + koff + ow + 16 * f + lq] =
              (f16)acc[m][f][r];
  }

  // ---- V: D[o][n] = sum_c Wv[o][c] x^T[n][c] + bv[o]
  {
    const f16* Wp = Wh + 2 * 65536;
    f32x4 acc[4][4];
    #pragma unroll
    for (int m = 0; m < 4; ++m)
      #pragma unroll
      for (int r = 0; r < 4; ++r) {
        float bf = bv[ow + 16 * m + 4 * g + r];
        #pragma unroll
        for (int f = 0; f < 4; ++f) acc[m][f][r] = bf;
      }
    #pragma unroll
    for (int kk = 0; kk < 8; ++kk) {
      int cb = kk * 32 + 8 * g;
      int s = 4 * kk + g;
      int p = (s & 0x10) | ((s ^ lq) & 0xF);
      half8 va[4], xb2[4];
      #pragma unroll
      for (int m = 0; m < 4; ++m)
        va[m] = *(const half8*)(Wp + (size_t)(ow + 16 * m + lq) * NC + cb);
      #pragma unroll
      for (int f = 0; f < 4; ++f)
        xb2[f] = *(const half8*)(&XS[16 * f + lq][p * 8]);
      #pragma unroll
      for (int m = 0; m < 4; ++m)
        #pragma unroll
        for (int f = 0; f < 4; ++f)
          acc[m][f] = mfma16(va[m], xb2[f], acc[m][f]);
    }
    #pragma unroll
    for (int m = 0; m < 4; ++m)
      #pragma unroll
      for (int f = 0; f < 4; ++f)
        #pragma unroll
        for (int r = 0; r < 4; ++r)
          V[((size_t)b * NC + ow + 16 * m + 4 * g + r) * NNN + n0 + 16 * f + lq] =
              (f16)acc[m][f][r];
  }
}

// -------- flash3: full-j, 512 blocks (2/CU), 4 waves x 16 q-rows, jt=32 of 32 j --------
__global__ __launch_bounds__(256, 2) void k_flash3(
    const f16* __restrict__ KQ, const f16* __restrict__ V,
    const f16* __restrict__ RT, float* __restrict__ out) {
  int bid = blockIdx.x;
  int swz = (bid & 7) * 64 + (bid >> 3);  // 64 blocks (4 batches) per XCD
  int b = swz >> 4;
  int i0 = (swz & 15) << 6;
  int tid = threadIdx.x;
  int wave = tid >> 6, lane = tid & 63;
  int lq = lane & 15, g = lane >> 4;
  int iw = i0 + 16 * wave;

  __shared__ f16 KQS[2][32][512];  // 64KB double-buffered j-tile (K||Q rows)
  __shared__ f16 Plds[4][16][40];  // wave-private P, padded (2-way banks)

  const f16* KQb = KQ + ((size_t)b << 19);
  const f16* Vb = V + ((size_t)b << 18);

  // ---- hoist A-fragments: [Q_i | R_i], 16 x half8, lives whole kernel
  half8 QA[16];
  #pragma unroll
  for (int kk = 0; kk < 8; ++kk)
    QA[kk] = *(const half8*)(KQb + ((size_t)(iw + lq) << 9) + 256 + kk * 32 + 8 * g);
  #pragma unroll
  for (int kk = 0; kk < 8; ++kk)
    QA[8 + kk] = *(const half8*)(RT + (size_t)(iw + lq) * NC + kk * 32 + 8 * g);

  f32x4 acc[16];
  #pragma unroll
  for (int cf = 0; cf < 16; ++cf) acc[cf] = (f32x4){0.f, 0.f, 0.f, 0.f};
  float m[4] = {-1e30f, -1e30f, -1e30f, -1e30f};
  float lsum[4] = {0.f, 0.f, 0.f, 0.f};  // per-lane partials (reduced at end)

#define STAGE(JT, BUF)                                                        \
  {                                                                           \
    _Pragma("unroll")                                                         \
    for (int rr = 0; rr < 8; ++rr) {                                          \
      int r_ = wave * 8 + rr;                                                 \
      int slot_ = (lane & 0x30) | ((lane ^ (r_ & 15)) & 0xF);                 \
      gload16(KQb + ((size_t)((JT) * 32 + r_) << 9) + slot_ * 8,              \
              &KQS[BUF][r_][0]);                                              \
    }                                                                         \
  }

  // prologue
  STAGE(0, 0);
  asm volatile("s_waitcnt vmcnt(0)" ::: "memory");
  __syncthreads();

  int cur = 0;
  #pragma unroll 1
  for (int jt = 0; jt < 32; ++jt) {
    int j0 = jt * 32;
    if (jt < 31) {
      if (cur) STAGE(jt + 1, 0) else STAGE(jt + 1, 1);
    }
    // ---- S = [Q_i|R_i].[K_j|Q_j], rows i=4g+r, cols j=16f+lq (f=0,1)
    f32x4 S0 = (f32x4){0.f, 0.f, 0.f, 0.f};
    f32x4 S1 = (f32x4){0.f, 0.f, 0.f, 0.f};
    const f16* KQSc = &KQS[cur][0][0];
    __builtin_amdgcn_s_setprio(1);
    #pragma unroll
    for (int kk = 0; kk < 16; ++kk) {
      int s = 4 * kk + g;
      int p = (s & 0x30) | ((s ^ lq) & 0xF);
      S0 = mfma16(QA[kk], *(const half8*)(KQSc + lq * 512 + p * 8), S0);
      S1 = mfma16(QA[kk], *(const half8*)(KQSc + (16 + lq) * 512 + p * 8), S1);
    }
    __builtin_amdgcn_s_setprio(0);

    // ---- online softmax with defer-max (THR=8)
    float t[4];
    #pragma unroll
    for (int r = 0; r < 4; ++r) {
      float tt = fmaxf(S0[r], S1[r]);
      tt = fmaxf(tt, __shfl_xor(tt, 1));
      tt = fmaxf(tt, __shfl_xor(tt, 2));
      tt = fmaxf(tt, __shfl_xor(tt, 4));
      tt = fmaxf(tt, __shfl_xor(tt, 8));
      t[r] = tt;
    }
    bool grow = (t[0] > m[0] + 8.f) | (t[1] > m[1] + 8.f) |
                (t[2] > m[2] + 8.f) | (t[3] > m[3] + 8.f);
    if (__builtin_amdgcn_ballot_w64(grow)) {
      float sc[4];
      #pragma unroll
      for (int r = 0; r < 4; ++r) {
        float mn = fmaxf(m[r], t[r]);
        sc[r] = __expf(m[r] - mn);
        m[r] = mn;
        lsum[r] *= sc[r];
      }
      int srcl = (lq >> 2) << 4;
      float s0 = __shfl(sc[0], srcl);
      float s1 = __shfl(sc[1], srcl);
      float s2 = __shfl(sc[2], srcl);
      float s3 = __shfl(sc[3], srcl);
      float sci = sel4(s0, s1, s2, s3, lq & 3);
      #pragma unroll
      for (int cf = 0; cf < 16; ++cf) {
        acc[cf][0] *= sci; acc[cf][1] *= sci; acc[cf][2] *= sci; acc[cf][3] *= sci;
      }
    }
    #pragma unroll
    for (int r = 0; r < 4; ++r) {
      float p0 = __expf(S0[r] - m[r]);
      float p1 = __expf(S1[r] - m[r]);
      S0[r] = p0; S1[r] = p1;
      lsum[r] += p0 + p1;
    }

    // ---- P -> LDS (wave-private), read back transposed as B-operand
    #pragma unroll
    for (int r = 0; r < 4; ++r) {
      Plds[wave][4 * g + r][lq] = (f16)S0[r];
      Plds[wave][4 * g + r][16 + lq] = (f16)S1[r];
    }
    asm volatile("s_waitcnt lgkmcnt(0)" ::: "memory");
    __builtin_amdgcn_sched_barrier(0);
    half8 pa = *(const half8*)(&Plds[wave][lq][8 * g]);

    // ---- O^T += V . P^T  (K=32)
    __builtin_amdgcn_s_setprio(1);
    #pragma unroll
    for (int cf = 0; cf < 16; ++cf) {
      half8 vv = *(const half8*)(Vb + ((size_t)(16 * cf + lq) << 10) + j0 + 8 * g);
      acc[cf] = mfma16(vv, pa, acc[cf]);
    }
    __builtin_amdgcn_s_setprio(0);

    asm volatile("s_waitcnt vmcnt(0)" ::: "memory");  // prefetch landed
    __syncthreads();
    cur ^= 1;
  }
#undef STAGE

  // ---- epilogue: reduce lsum across 16 lanes, normalize, store f32 out
  #pragma unroll
  for (int r = 0; r < 4; ++r) {
    float l = lsum[r];
    l += __shfl_xor(l, 1);
    l += __shfl_xor(l, 2);
    l += __shfl_xor(l, 4);
    l += __shfl_xor(l, 8);
    lsum[r] = 1.f / l;
  }
  float li;
  {
    int srcl = (lq >> 2) << 4;
    float l0 = __shfl(lsum[0], srcl);
    float l1 = __shfl(lsum[1], srcl);
    float l2 = __shfl(lsum[2], srcl);
    float l3 = __shfl(lsum[3], srcl);
    li = sel4(l0, l1, l2, l3, lq & 3);
  }
  #pragma unroll
  for (int cf = 0; cf < 16; ++cf)
    #pragma unroll
    for (int r = 0; r < 4; ++r)
      out[((size_t)(b * NC + 16 * cf + 4 * g + r) << 10) + iw + lq] = acc[cf][r] * li;
}

// ---------------- launch ----------------
extern "C" void kernel_launch(void* const* d_in, const int* in_sizes, int n_in,
                              void* d_out, int out_size, void* d_ws, size_t ws_size,
                              hipStream_t stream) {
  const float* x = (const float*)d_in[0];
  const float* Wq = (const float*)d_in[1];
  const float* bq = (const float*)d_in[2];
  const float* Wk = (const float*)d_in[3];
  const float* bk = (const float*)d_in[4];
  const float* Wv = (const float*)d_in[5];
  const float* bv = (const float*)d_in[6];
  const float* relh = (const float*)d_in[7];
  const float* relw = (const float*)d_in[8];

  char* ws = (char*)d_ws;
  const size_t MB = 1 << 20;
  f16* KQ = (f16*)(ws);                         // 32MB
  f16* V = (f16*)(ws + 32 * MB);                // 16MB
  f16* RT = (f16*)(ws + 48 * MB);               // 512KB
  f16* Wh = (f16*)(ws + 48 * MB + 512 * 1024);  // 384KB

  k_prep<<<dim3(1216), dim3(256), 0, stream>>>(Wq, Wk, Wv, relh, relw, Wh, RT);
  k_proj<<<dim3(512), dim3(256), 0, stream>>>(x, Wh, bq, bk, bv, KQ, V);
  k_flash3<<<dim3(512), dim3(256), 0, stream>>>(KQ, V, RT, (float*)d_out);
}